// Round 10
// baseline (96.487 us; speedup 1.0000x reference)
//
#include <hip/hip_runtime.h>
#include <math.h>

#define BATCH 8
#define H 256
#define W 256
#define NPIX (BATCH * H * W)
#define NBLK2 1024   // K2: 8 img x 4 colstrips x 32 rowstrips

__device__ __forceinline__ float bce_logits(float p, float t) {
    return fmaxf(p, 0.0f) - p * t + log1pf(expf(-fabsf(p)));
}

// K1: row EDT^2 via ballot masks, k-quad-interleaved output:
// gi4[(b*64+k4)*256 + w] = float4(g2[4k4+0][w], .., g2[4k4+3][w]).
// Block = (image, row-quad). Block 0 zeroes K2's ticket counter.
__global__ void __launch_bounds__(256) row_edt4(const float* __restrict__ target,
                                                float4* __restrict__ gi4,
                                                unsigned int* __restrict__ counter) {
    if (blockIdx.x == 0 && threadIdx.x == 0) *counter = 0u;
    __shared__ unsigned long long mlds[4][4];
    const int tid = threadIdx.x;
    const int v = tid >> 6, l = tid & 63;
    const float* imgr = target + (size_t)blockIdx.x * 4 * W;

    #pragma unroll
    for (int j = 0; j < 4; ++j) {
        float t = imgr[j * W + tid];
        unsigned long long m = __ballot(t == 0.0f);
        if (l == 0) mlds[j][v] = m;
    }
    __syncthreads();

    const int p = tid;                     // column
    float g[4];
    #pragma unroll
    for (int j = 0; j < 4; ++j) {
        unsigned long long mw[4] = {mlds[j][0], mlds[j][1], mlds[j][2], mlds[j][3]};
        int best = 1 << 20;
        #pragma unroll
        for (int w = 0; w < 4; ++w) {
            const int rel = p - (w << 6);
            const unsigned long long m = mw[w];
            unsigned long long mlo = (rel < 0)  ? 0ull
                                   : (rel >= 63) ? m : (m & ((2ull << rel) - 1ull));
            unsigned long long mhi = (rel <= 0) ? m
                                   : (rel > 63)  ? 0ull : (m & (~0ull << rel));
            if (mlo) best = min(best, rel - (63 - __builtin_clzll(mlo)));
            if (mhi) best = min(best, __builtin_ctzll(mhi) - rel);
        }
        float d = (best > 255) ? 1e4f : (float)best;    // INF per reference
        g[j] = d * d;
    }
    gi4[(size_t)blockIdx.x * 256 + tid] = make_float4(g[0], g[1], g[2], g[3]);
}

// K2: column envelope + fused BCE + last-block final fold.
// Lane = column (64 cols/block), thread covers 2 rows; 1024 blocks (4 waves/SIMD).
// Inner loop: one coalesced L2-hot float4 load per 4 k; zero LDS, no barrier.
__global__ void __launch_bounds__(256) envelope_bce(
        const float4* __restrict__ gi4, const float* __restrict__ pred,
        const float* __restrict__ target,
        float* __restrict__ pmx, float* __restrict__ psb, float* __restrict__ psdb,
        unsigned int* __restrict__ counter, float* __restrict__ out) {
    __shared__ float red[3][4];
    __shared__ unsigned int lastFlag;
    const int tid = threadIdx.x;
    const int wv = tid >> 6, l = tid & 63;
    const int b  = blockIdx.x >> 7;               // image (128 blocks each)
    const int cs = (blockIdx.x >> 5) & 3;         // column strip (64 cols)
    const int rs = blockIdx.x & 31;               // row strip (8 rows)
    const int c  = (cs << 6) + l;                 // this lane's column
    const int i0 = (rs << 3) + (wv << 1);         // this lane's rows: i0, i0+1

    const float4* gp = gi4 + (size_t)b * 64 * 256 + c;

    float acc0 = 3.0e38f, acc1 = 3.0e38f;
    // fmaf(d,d,g) == reference g2 + (i-k)^2 (exact integers < 2^24, one rounding).
    float d = (float)i0;                          // i0 - 4*k4
    #pragma unroll 8
    for (int k4 = 0; k4 < 64; ++k4) {
        float4 g = gp[(size_t)k4 * 256];          // g2 at k=4k4..4k4+3, col c
        float e = d;                              // row i0
        acc0 = fminf(acc0, fminf(fmaf(e, e, g.x), fmaf(e - 1.0f, e - 1.0f, g.y)));
        acc0 = fminf(acc0, fminf(fmaf(e - 2.0f, e - 2.0f, g.z), fmaf(e - 3.0f, e - 3.0f, g.w)));
        float f = d + 1.0f;                       // row i0+1
        acc1 = fminf(acc1, fminf(fmaf(f, f, g.x), fmaf(f - 1.0f, f - 1.0f, g.y)));
        acc1 = fminf(acc1, fminf(fmaf(f - 2.0f, f - 2.0f, g.z), fmaf(f - 3.0f, f - 3.0f, g.w)));
        d -= 4.0f;
    }

    // ---- Epilogue: BCE at the 2 (row, c) pixels (coalesced across lanes) ----
    const size_t po = ((size_t)(b * H + i0)) * W + c;
    float p0 = pred[po], p1 = pred[po + W];
    float t0 = target[po], t1 = target[po + W];

    float mx = fmaxf(acc0, acc1);
    float b0 = bce_logits(p0, t0), b1 = bce_logits(p1, t1);
    float sb  = b0 + b1;
    float sdb = sqrtf(acc0) * b0 + sqrtf(acc1) * b1;

    #pragma unroll
    for (int o = 32; o > 0; o >>= 1) {
        mx  = fmaxf(mx, __shfl_down(mx, o, 64));
        sb  += __shfl_down(sb, o, 64);
        sdb += __shfl_down(sdb, o, 64);
    }
    if (l == 0) { red[0][wv] = mx; red[1][wv] = sb; red[2][wv] = sdb; }
    __syncthreads();
    if (tid == 0) {
        pmx [blockIdx.x] = fmaxf(fmaxf(red[0][0], red[0][1]), fmaxf(red[0][2], red[0][3]));
        psb [blockIdx.x] = (red[1][0] + red[1][1]) + (red[1][2] + red[1][3]);
        psdb[blockIdx.x] = (red[2][0] + red[2][1]) + (red[2][2] + red[2][3]);
        __threadfence();                          // release partials device-wide
        unsigned int t = atomicAdd(counter, 1u);  // device-scope
        lastFlag = (t == NBLK2 - 1) ? 1u : 0u;
    }
    __syncthreads();

    // ---- Last block: fold 1024 partials -> scalar (deterministic tree) ----
    if (lastFlag) {
        __threadfence();                          // acquire
        const int img = tid >> 5, j = tid & 31;   // 8 images x 32 threads
        float fmx = 0.0f, fsb = 0.0f, fsdb = 0.0f;
        #pragma unroll
        for (int q = 0; q < 4; ++q) {
            const int e = (img << 7) + j + (q << 5);
            fmx  = fmaxf(fmx, pmx[e]);
            fsb  += psb[e];
            fsdb += psdb[e];
        }
        #pragma unroll
        for (int o = 16; o > 0; o >>= 1) {        // width-32 stays per-image
            fmx  = fmaxf(fmx, __shfl_down(fmx, o, 32));
            fsb  += __shfl_down(fsb, o, 32);
            fsdb += __shfl_down(fsdb, o, 32);
        }
        __shared__ float cimg[8], simg[8];
        if (j == 0) {
            cimg[img] = fsdb / (sqrtf(fmx) + 1e-7f);   // sqrt commutes with max
            simg[img] = fsb;
        }
        __syncthreads();
        if (tid == 0) {
            float tot = 0.0f;
            #pragma unroll
            for (int i = 0; i < 8; ++i) tot += simg[i] + cimg[i];
            out[0] = tot * (1.0f / (float)NPIX);
        }
    }
}

extern "C" void kernel_launch(void* const* d_in, const int* in_sizes, int n_in,
                              void* d_out, int out_size, void* d_ws, size_t ws_size,
                              hipStream_t stream) {
    const float* pred   = (const float*)d_in[0];
    const float* target = (const float*)d_in[1];

    float4* gi4 = (float4*)d_ws;                                  // 2 MB
    float* pmx  = (float*)((char*)d_ws + (size_t)BATCH * 64 * 256 * sizeof(float4));
    float* psb  = pmx + NBLK2;
    float* psdb = psb + NBLK2;
    unsigned int* counter = (unsigned int*)(psdb + NBLK2);

    row_edt4<<<BATCH * 64, 256, 0, stream>>>(target, gi4, counter);   // 512 blocks
    envelope_bce<<<NBLK2, 256, 0, stream>>>(gi4, pred, target, pmx, psb, psdb,
                                            counter, (float*)d_out);
}

// Round 11
// 67.383 us; speedup vs baseline: 1.4319x; 1.4319x over previous
//
#include <hip/hip_runtime.h>
#include <math.h>

#define BATCH 8
#define H 256
#define W 256
#define NPIX (BATCH * H * W)
#define NBLK2 512   // K2 blocks: 8 img x 4 colstrips x 16 rowstrips

__device__ __forceinline__ float bce_logits(float p, float t) {
    return fmaxf(p, 0.0f) - p * t + log1pf(expf(-fabsf(p)));
}

// K1: row EDT^2 via ballot masks, plain layout g2[b*65536 + r*256 + w].
// Block = (image, row-quad): rows 4k4..4k4+3, thread = column.
__global__ void __launch_bounds__(256) row_edt(const float* __restrict__ target,
                                               float* __restrict__ g2) {
    __shared__ unsigned long long mlds[4][4];
    const int tid = threadIdx.x;
    const int v = tid >> 6, l = tid & 63;
    const float* imgr = target + (size_t)blockIdx.x * 4 * W;

    #pragma unroll
    for (int j = 0; j < 4; ++j) {
        float t = imgr[j * W + tid];
        unsigned long long m = __ballot(t == 0.0f);
        if (l == 0) mlds[j][v] = m;
    }
    __syncthreads();

    const int p = tid;                     // column
    #pragma unroll
    for (int j = 0; j < 4; ++j) {
        unsigned long long mw[4] = {mlds[j][0], mlds[j][1], mlds[j][2], mlds[j][3]};
        int best = 1 << 20;
        #pragma unroll
        for (int w = 0; w < 4; ++w) {
            const int rel = p - (w << 6);
            const unsigned long long m = mw[w];
            unsigned long long mlo = (rel < 0)  ? 0ull
                                   : (rel >= 63) ? m : (m & ((2ull << rel) - 1ull));
            unsigned long long mhi = (rel <= 0) ? m
                                   : (rel > 63)  ? 0ull : (m & (~0ull << rel));
            if (mlo) best = min(best, rel - (63 - __builtin_clzll(mlo)));
            if (mhi) best = min(best, __builtin_ctzll(mhi) - rel);
        }
        float d = (best > 255) ? 1e4f : (float)best;    // INF per reference
        g2[(size_t)blockIdx.x * 4 * W + j * W + tid] = d * d;
    }
}

// K2: column envelope with BIT-EXACT early exit + fused BCE.
// Lane = column, thread owns rows i0..i0+3. Two-pointer outward k-scan:
// skip k once (min-dist-to-rowgroup)^2 > max(acc) — skipped candidates
// satisfy g2+(r-k)^2 >= (r-k)^2 > acc_r, so the min (and bits) are unchanged.
__global__ void __launch_bounds__(256) envelope_bce(
        const float* __restrict__ g2, const float* __restrict__ pred,
        const float* __restrict__ target,
        float* __restrict__ pmx, float* __restrict__ psb, float* __restrict__ psdb) {
    __shared__ float red[3][4];
    const int tid = threadIdx.x;
    const int wv = tid >> 6, l = tid & 63;
    const int b  = blockIdx.x >> 6;               // image
    const int cs = (blockIdx.x >> 4) & 3;         // column strip (64 cols)
    const int rs = blockIdx.x & 15;               // row strip (16 rows)
    const int c  = (cs << 6) + l;                 // this lane's column
    const int i0 = (rs << 4) + (wv << 2);         // rows i0..i0+3

    // issue BCE pixel loads early (consumed at the end)
    const float* pp = pred   + ((size_t)(b * H + i0)) * W + c;
    const float* tp = target + ((size_t)(b * H + i0)) * W + c;
    float p0 = pp[0], p1 = pp[W], p2 = pp[2 * W], p3 = pp[3 * W];
    float t0 = tp[0], t1 = tp[W], t2 = tp[2 * W], t3 = tp[3 * W];

    const float* gcol = g2 + (size_t)b * H * W + c;

    float acc0 = 3.0e38f, acc1 = 3.0e38f, acc2 = 3.0e38f, acc3 = 3.0e38f;
    int kd = i0 + 1, ku = i0 + 2;                 // outward two-pointer
    // fd_r = r - kd, fu_r = ku - r  (maintained incrementally; fmaf exact)
    float fd0 = (float)(i0 - kd), fu0 = (float)(ku - i0);
    for (;;) {
        if (kd >= 0) {
            float g = gcol[(size_t)kd * W];
            acc0 = fminf(acc0, fmaf(fd0, fd0, g));
            float fd1 = fd0 + 1.0f, fd2 = fd0 + 2.0f, fd3 = fd0 + 3.0f;
            acc1 = fminf(acc1, fmaf(fd1, fd1, g));
            acc2 = fminf(acc2, fmaf(fd2, fd2, g));
            acc3 = fminf(acc3, fmaf(fd3, fd3, g));
        }
        if (ku <= 255) {
            float g = gcol[(size_t)ku * W];
            float fu1 = fu0 - 1.0f, fu2 = fu0 - 2.0f, fu3 = fu0 - 3.0f;
            acc0 = fminf(acc0, fmaf(fu0, fu0, g));
            acc1 = fminf(acc1, fmaf(fu1, fu1, g));
            acc2 = fminf(acc2, fmaf(fu2, fu2, g));
            acc3 = fminf(acc3, fmaf(fu3, fu3, g));
        }
        --kd; ++ku; fd0 += 1.0f; fu0 += 1.0f;
        // conservative alive check: min dist from kd (resp. ku) to row group
        float maxacc = fmaxf(fmaxf(acc0, acc1), fmaxf(acc2, acc3));
        float dn = (float)(i0 - kd);              // >= 1
        float up = (float)(ku - (i0 + 3));        // >= 1
        bool alive = (kd >= 0 && dn * dn <= maxacc) || (ku <= 255 && up * up <= maxacc);
        if (!__any(alive)) break;
    }

    // ---- Epilogue: fused BCE + per-block partials ----
    float mx = fmaxf(fmaxf(acc0, acc1), fmaxf(acc2, acc3));
    float b0 = bce_logits(p0, t0), b1 = bce_logits(p1, t1);
    float b2 = bce_logits(p2, t2), b3 = bce_logits(p3, t3);
    float sb  = (b0 + b1) + (b2 + b3);
    float sdb = (sqrtf(acc0) * b0 + sqrtf(acc1) * b1)
              + (sqrtf(acc2) * b2 + sqrtf(acc3) * b3);

    #pragma unroll
    for (int o = 32; o > 0; o >>= 1) {
        mx  = fmaxf(mx, __shfl_down(mx, o, 64));
        sb  += __shfl_down(sb, o, 64);
        sdb += __shfl_down(sdb, o, 64);
    }
    if (l == 0) { red[0][wv] = mx; red[1][wv] = sb; red[2][wv] = sdb; }
    __syncthreads();
    if (tid == 0) {
        pmx [blockIdx.x] = fmaxf(fmaxf(red[0][0], red[0][1]), fmaxf(red[0][2], red[0][3]));
        psb [blockIdx.x] = (red[1][0] + red[1][1]) + (red[1][2] + red[1][3]);
        psdb[blockIdx.x] = (red[2][0] + red[2][1]) + (red[2][2] + red[2][3]);
    }
}

// K3: 512 partials -> scalar. Images are contiguous 64-block runs.
__global__ void final_reduce(const float* __restrict__ pmx, const float* __restrict__ psb,
                             const float* __restrict__ psdb, float* __restrict__ out) {
    const int tid = threadIdx.x;
    const int img = tid >> 5, j = tid & 31;        // 8 images x 32 threads
    const int e0 = (img << 6) + j, e1 = e0 + 32;
    float mx  = fmaxf(pmx[e0], pmx[e1]);
    float sb  = psb[e0] + psb[e1];
    float sdb = psdb[e0] + psdb[e1];
    #pragma unroll
    for (int o = 16; o > 0; o >>= 1) {             // width-32 groups stay per-image
        mx  = fmaxf(mx, __shfl_down(mx, o, 32));
        sb  += __shfl_down(sb, o, 32);
        sdb += __shfl_down(sdb, o, 32);
    }
    __shared__ float cimg[8], simg[8];
    if (j == 0) {
        cimg[img] = sdb / (sqrtf(mx) + 1e-7f);     // sqrt commutes with max
        simg[img] = sb;
    }
    __syncthreads();
    if (tid == 0) {
        float tot = 0.0f;
        #pragma unroll
        for (int i = 0; i < 8; ++i) tot += simg[i] + cimg[i];
        out[0] = tot * (1.0f / (float)NPIX);
    }
}

extern "C" void kernel_launch(void* const* d_in, const int* in_sizes, int n_in,
                              void* d_out, int out_size, void* d_ws, size_t ws_size,
                              hipStream_t stream) {
    const float* pred   = (const float*)d_in[0];
    const float* target = (const float*)d_in[1];

    float* g2   = (float*)d_ws;                                   // 2 MB
    float* pmx  = (float*)((char*)d_ws + (size_t)NPIX * sizeof(float));
    float* psb  = pmx + NBLK2;
    float* psdb = psb + NBLK2;

    row_edt<<<BATCH * 64, 256, 0, stream>>>(target, g2);          // 512 blocks
    envelope_bce<<<NBLK2, 256, 0, stream>>>(g2, pred, target, pmx, psb, psdb);
    final_reduce<<<1, 256, 0, stream>>>(pmx, psb, psdb, (float*)d_out);
}

// Round 12
// 65.342 us; speedup vs baseline: 1.4767x; 1.0312x over previous
//
#include <hip/hip_runtime.h>
#include <math.h>

#define BATCH 8
#define H 256
#define W 256
#define NPIX (BATCH * H * W)
#define NBLK2 1024  // K2: 8 img x 4 colstrips x 32 rowstrips

__device__ __forceinline__ float bce_logits(float p, float t) {
    return fmaxf(p, 0.0f) - p * t + log1pf(expf(-fabsf(p)));
}

// K1: row EDT^2 via ballot masks, plain layout g2[b*65536 + r*256 + w].
// Block = (image, row-quad): rows 4q..4q+3, thread = column.
__global__ void __launch_bounds__(256) row_edt(const float* __restrict__ target,
                                               float* __restrict__ g2) {
    __shared__ unsigned long long mlds[4][4];
    const int tid = threadIdx.x;
    const int v = tid >> 6, l = tid & 63;
    const float* imgr = target + (size_t)blockIdx.x * 4 * W;

    #pragma unroll
    for (int j = 0; j < 4; ++j) {
        float t = imgr[j * W + tid];
        unsigned long long m = __ballot(t == 0.0f);
        if (l == 0) mlds[j][v] = m;
    }
    __syncthreads();

    const int p = tid;                     // column
    #pragma unroll
    for (int j = 0; j < 4; ++j) {
        unsigned long long mw[4] = {mlds[j][0], mlds[j][1], mlds[j][2], mlds[j][3]};
        int best = 1 << 20;
        #pragma unroll
        for (int w = 0; w < 4; ++w) {
            const int rel = p - (w << 6);
            const unsigned long long m = mw[w];
            unsigned long long mlo = (rel < 0)  ? 0ull
                                   : (rel >= 63) ? m : (m & ((2ull << rel) - 1ull));
            unsigned long long mhi = (rel <= 0) ? m
                                   : (rel > 63)  ? 0ull : (m & (~0ull << rel));
            if (mlo) best = min(best, rel - (63 - __builtin_clzll(mlo)));
            if (mhi) best = min(best, __builtin_ctzll(mhi) - rel);
        }
        float d = (best > 255) ? 1e4f : (float)best;    // INF per reference
        g2[(size_t)blockIdx.x * 4 * W + j * W + tid] = d * d;
    }
}

// K2: column envelope, pipelined prologue + bit-exact early-exit tail, fused BCE.
// Lane = column; thread owns rows i0, i0+1. Prologue: P outward steps with
// clamped addresses + OOB sentinel -> all 2P loads in flight, no per-step checks.
__global__ void __launch_bounds__(256) envelope_bce(
        const float* __restrict__ g2, const float* __restrict__ pred,
        const float* __restrict__ target,
        float* __restrict__ pmx, float* __restrict__ psb, float* __restrict__ psdb) {
    __shared__ float red[3][4];
    const int tid = threadIdx.x;
    const int wv = tid >> 6, l = tid & 63;
    const int b  = blockIdx.x >> 7;               // image (128 blocks each)
    const int cs = (blockIdx.x >> 5) & 3;         // column strip (64 cols)
    const int rs = blockIdx.x & 31;               // row strip (8 rows)
    const int c  = (cs << 6) + l;                 // this lane's column
    const int i0 = (rs << 3) + (wv << 1);         // rows i0, i0+1

    // BCE pixel loads issued early (consumed at the end)
    const size_t po = ((size_t)(b * H + i0)) * W + c;
    float p0 = pred[po], p1 = pred[po + W];
    float t0 = target[po], t1 = target[po + W];

    const float* gcol = g2 + (size_t)b * H * W + c;

    float acc0 = 3.0e38f, acc1 = 3.0e38f;
    // ---- Prologue: P steps each way, unconditional (clamped + sentinel) ----
    // Candidates kd_s = i0+1-s (s=0..P-1) cover k<=i0+1; ku_s = i0+2+s cover k>=i0+2.
    // OOB candidates get g=3e38: e^2+3e38 < FLT_MAX, never the min. fmaf == ref.
    const int P = 10;
    #pragma unroll
    for (int s = 0; s < P; ++s) {
        const int kd = i0 + 1 - s;
        const int ku = i0 + 2 + s;
        float gd = gcol[(size_t)max(kd, 0) * W];
        float gu = gcol[(size_t)min(ku, 255) * W];
        if (kd < 0)   gd = 3.0e38f;
        if (ku > 255) gu = 3.0e38f;
        const float ed0 = (float)(s - 1), ed1 = (float)s;       // r - kd, r=i0,i0+1
        const float eu0 = (float)(s + 2), eu1 = (float)(s + 1); // ku - r
        acc0 = fminf(acc0, fminf(fmaf(ed0, ed0, gd), fmaf(eu0, eu0, gu)));
        acc1 = fminf(acc1, fminf(fmaf(ed1, ed1, gd), fmaf(eu1, eu1, gu)));
    }

    // ---- Tail: exact early-exit two-pointer scan (rarely runs) ----
    int kd = i0 + 1 - P, ku = i0 + 2 + P;
    float fd0 = (float)(i0 - kd);                 // r=i0 vs kd
    float fu0 = (float)(ku - i0);                 // ku vs r=i0
    for (;;) {
        float maxacc = fmaxf(acc0, acc1);
        float dn = (float)(i0 - kd);              // min dist from group to kd
        float up = (float)(ku - (i0 + 1));        // min dist from group to ku
        bool alive = (kd >= 0 && dn * dn <= maxacc) || (ku <= 255 && up * up <= maxacc);
        if (!__any(alive)) break;
        if (kd >= 0) {
            float g = gcol[(size_t)kd * W];
            acc0 = fminf(acc0, fmaf(fd0, fd0, g));
            float fd1 = fd0 + 1.0f;
            acc1 = fminf(acc1, fmaf(fd1, fd1, g));
        }
        if (ku <= 255) {
            float g = gcol[(size_t)ku * W];
            float fu1 = fu0 - 1.0f;
            acc0 = fminf(acc0, fmaf(fu0, fu0, g));
            acc1 = fminf(acc1, fmaf(fu1, fu1, g));
        }
        --kd; ++ku; fd0 += 1.0f; fu0 += 1.0f;
    }

    // ---- Epilogue: fused BCE + per-block partials ----
    float mx = fmaxf(acc0, acc1);
    float b0 = bce_logits(p0, t0), b1 = bce_logits(p1, t1);
    float sb  = b0 + b1;
    float sdb = sqrtf(acc0) * b0 + sqrtf(acc1) * b1;

    #pragma unroll
    for (int o = 32; o > 0; o >>= 1) {
        mx  = fmaxf(mx, __shfl_down(mx, o, 64));
        sb  += __shfl_down(sb, o, 64);
        sdb += __shfl_down(sdb, o, 64);
    }
    if (l == 0) { red[0][wv] = mx; red[1][wv] = sb; red[2][wv] = sdb; }
    __syncthreads();
    if (tid == 0) {
        pmx [blockIdx.x] = fmaxf(fmaxf(red[0][0], red[0][1]), fmaxf(red[0][2], red[0][3]));
        psb [blockIdx.x] = (red[1][0] + red[1][1]) + (red[1][2] + red[1][3]);
        psdb[blockIdx.x] = (red[2][0] + red[2][1]) + (red[2][2] + red[2][3]);
    }
}

// K3: 1024 partials -> scalar. Images are contiguous 128-block runs.
__global__ void final_reduce(const float* __restrict__ pmx, const float* __restrict__ psb,
                             const float* __restrict__ psdb, float* __restrict__ out) {
    const int tid = threadIdx.x;
    const int img = tid >> 5, j = tid & 31;        // 8 images x 32 threads
    float mx = 0.0f, sb = 0.0f, sdb = 0.0f;
    #pragma unroll
    for (int q = 0; q < 4; ++q) {
        const int e = (img << 7) + j + (q << 5);
        mx  = fmaxf(mx, pmx[e]);
        sb  += psb[e];
        sdb += psdb[e];
    }
    #pragma unroll
    for (int o = 16; o > 0; o >>= 1) {             // width-32 groups stay per-image
        mx  = fmaxf(mx, __shfl_down(mx, o, 32));
        sb  += __shfl_down(sb, o, 32);
        sdb += __shfl_down(sdb, o, 32);
    }
    __shared__ float cimg[8], simg[8];
    if (j == 0) {
        cimg[img] = sdb / (sqrtf(mx) + 1e-7f);     // sqrt commutes with max
        simg[img] = sb;
    }
    __syncthreads();
    if (tid == 0) {
        float tot = 0.0f;
        #pragma unroll
        for (int i = 0; i < 8; ++i) tot += simg[i] + cimg[i];
        out[0] = tot * (1.0f / (float)NPIX);
    }
}

extern "C" void kernel_launch(void* const* d_in, const int* in_sizes, int n_in,
                              void* d_out, int out_size, void* d_ws, size_t ws_size,
                              hipStream_t stream) {
    const float* pred   = (const float*)d_in[0];
    const float* target = (const float*)d_in[1];

    float* g2   = (float*)d_ws;                                   // 8 MB
    float* pmx  = (float*)((char*)d_ws + (size_t)NPIX * sizeof(float));
    float* psb  = pmx + NBLK2;
    float* psdb = psb + NBLK2;

    row_edt<<<BATCH * 64, 256, 0, stream>>>(target, g2);          // 512 blocks
    envelope_bce<<<NBLK2, 256, 0, stream>>>(g2, pred, target, pmx, psb, psdb);
    final_reduce<<<1, 256, 0, stream>>>(pmx, psb, psdb, (float*)d_out);
}